// Round 4
// baseline (310.117 us; speedup 1.0000x reference)
//
#include <hip/hip_runtime.h>
#include <math.h>

// Problem constants: N=65536 rows, D=512 features, K=5 centroids.
#define LFR_N 65536
#define LFR_D 512
#define LFR_K 5
#define TPB   256                 // threads per block
#define RPB   128                 // rows per block (2 threads per row)
#define NBLK  (LFR_N / RPB)       // 512 blocks = 2 per CU (LDS capacity 3/CU)
#define CH    32                  // floats of D staged per chunk
#define NCH   (LFR_D / CH)        // 16 chunks
#define STRIDE (CH + 4)           // 36 words/row: 144B = 16B-aligned, odd multiple of 4
                                  // -> balanced b128 bank quads (8 lanes per 4-bank quad = minimum)

// R0-R2 post-mortem: wave-per-row + 6-step butterfly is latency-bound at 2.5 TB/s
// regardless of per-wave ILP. This version: thread-per-row-half, x staged via LDS
// (coalesced), c' = alpha*c staged in LDS (broadcast reads), dist via shift-invariant
// form B_k - 2*dot_k (Sum alpha*x^2 cancels in softmax). Zero cross-lane ops in the
// chunk loop; ONE shfl_xor(32) at the end merges row halves. Softmax per-thread.
__global__ __launch_bounds__(TPB) void lfr_kernel(
    const float* __restrict__ x,        // (N, D)
    const float* __restrict__ alpha,    // (D,)
    const float* __restrict__ w,        // (K, 1)
    const float* __restrict__ cent,     // (K, D)
    float* __restrict__ out_map,        // (N, K)
    float* __restrict__ out_rec,        // (N, D)
    float* __restrict__ out_pred)       // (N,)
{
    __shared__ float xbuf[2][RPB * STRIDE];   // 2 x 18,432 B = 36,864 B
    __shared__ float cbuf[LFR_K * LFR_D];     // 10,240 B : c' = alpha .* c

    const int t   = threadIdx.x;
    const int wv  = t >> 6;          // wave 0..3
    const int l   = t & 63;          // lane
    const int rb0 = blockIdx.x * RPB;

    const float4* __restrict__ x4 = (const float4*)x;

    // ---- stage c' = alpha .* c into LDS (640 float4, 2.5 per thread) ----
    {
        const float4* c4 = (const float4*)cent;
        const float4* a4 = (const float4*)alpha;
        #pragma unroll
        for (int i = 0; i < 3; ++i) {
            int f = i * TPB + t;                 // 0..767, need <640
            if (f < LFR_K * LFR_D / 4) {
                int k = f >> 7, d4 = f & 127;
                float4 cv = c4[k * 128 + d4];
                float4 av = a4[d4];
                float4 o;
                o.x = cv.x * av.x; o.y = cv.y * av.y;
                o.z = cv.z * av.z; o.w = cv.w * av.w;
                ((float4*)cbuf)[f] = o;
            }
        }
    }

    // ---- stage x chunk 0: 128 rows x 32 floats, 4 float4 per thread, coalesced ----
    #pragma unroll
    for (int i = 0; i < 4; ++i) {
        int f = i * TPB + t;                     // 0..1023
        int r = f >> 3, q = f & 7;
        float4 v = x4[(size_t)(rb0 + r) * 128 + q];          // chunk 0
        ((float4*)&xbuf[0][r * STRIDE])[q] = v;
    }
    __syncthreads();

    // ---- B_k = sum_d alpha*c^2 = sum_d c'*c (once per block, redundant per wave) ----
    float Bk[LFR_K];
    {
        const int db = l * 8;
        #pragma unroll
        for (int k = 0; k < LFR_K; ++k) {
            float s = 0.0f;
            #pragma unroll
            for (int j = 0; j < 8; ++j)
                s = fmaf(cbuf[k * LFR_D + db + j], cent[k * LFR_D + db + j], s);
            Bk[k] = s;
        }
        #pragma unroll
        for (int off = 32; off > 0; off >>= 1)
            #pragma unroll
            for (int k = 0; k < LFR_K; ++k)
                Bk[k] += __shfl_xor(Bk[k], off);
    }

    // ---- main chunk loop: thread (row R, half h) accumulates 5 dots, no cross-lane ----
    const int R = wv * 32 + (l & 31);   // row-local 0..127
    const int h = l >> 5;               // half 0/1: d in [32c+16h, 32c+16h+16)
    float dot[LFR_K] = {0.f, 0.f, 0.f, 0.f, 0.f};

    for (int c = 0; c < NCH; ++c) {
        const int cur = c & 1;
        float4 pf[4];
        if (c + 1 < NCH) {                       // prefetch next chunk (in flight over compute)
            #pragma unroll
            for (int i = 0; i < 4; ++i) {
                int f = i * TPB + t, r = f >> 3, q = f & 7;
                pf[i] = x4[(size_t)(rb0 + r) * 128 + (c + 1) * 8 + q];
            }
        }
        const float* xb = &xbuf[cur][R * STRIDE + 16 * h];
        #pragma unroll
        for (int j = 0; j < 4; ++j) {
            float4 xq = ((const float4*)xb)[j];
            #pragma unroll
            for (int k = 0; k < LFR_K; ++k) {
                float4 cq = ((const float4*)&cbuf[k * LFR_D + c * CH + 16 * h])[j];
                dot[k] = fmaf(xq.x, cq.x, dot[k]);
                dot[k] = fmaf(xq.y, cq.y, dot[k]);
                dot[k] = fmaf(xq.z, cq.z, dot[k]);
                dot[k] = fmaf(xq.w, cq.w, dot[k]);
            }
        }
        if (c + 1 < NCH) {
            #pragma unroll
            for (int i = 0; i < 4; ++i) {
                int f = i * TPB + t, r = f >> 3, q = f & 7;
                ((float4*)&xbuf[cur ^ 1][r * STRIDE])[q] = pf[i];
            }
        }
        __syncthreads();
    }

    // ---- merge halves: ONE shuffle step; then per-thread softmax ----
    #pragma unroll
    for (int k = 0; k < LFR_K; ++k)
        dot[k] += __shfl_xor(dot[k], 32);

    float dist[LFR_K], m[LFR_K];
    #pragma unroll
    for (int k = 0; k < LFR_K; ++k) dist[k] = Bk[k] - 2.0f * dot[k];
    float mx = dist[0];
    #pragma unroll
    for (int k = 1; k < LFR_K; ++k) mx = fmaxf(mx, dist[k]);
    float s = 0.0f;
    #pragma unroll
    for (int k = 0; k < LFR_K; ++k) { m[k] = __expf(dist[k] - mx); s += m[k]; }
    float inv = 1.0f / s;
    #pragma unroll
    for (int k = 0; k < LFR_K; ++k) m[k] *= inv;

    // ---- map + pred stores (half-0 threads only) + m -> LDS for phase 2 ----
    float* mb = &xbuf[0][0];   // 128 rows x 8 floats (4 KB), xbuf free after loop
    if (h == 0) {
        float* mp = out_map + (size_t)(rb0 + R) * LFR_K;
        mp[0] = m[0]; mp[1] = m[1]; mp[2] = m[2]; mp[3] = m[3]; mp[4] = m[4];
        float p = 0.0f;
        #pragma unroll
        for (int k = 0; k < LFR_K; ++k) {
            float sw = 1.0f / (1.0f + __expf(-w[k]));
            p = fmaf(m[k], sw, p);
        }
        out_pred[rb0 + R] = p;
        #pragma unroll
        for (int k = 0; k < LFR_K; ++k) mb[R * 8 + k] = m[k];
    }
    __syncthreads();

    // ---- phase 2: reconstruct, wave-per-row, lane covers 8 d's ----
    float cc[LFR_K][8];
    const int d0 = l * 8;
    #pragma unroll
    for (int k = 0; k < LFR_K; ++k) {
        float4 a = *(const float4*)(cent + k * LFR_D + d0);
        float4 b = *(const float4*)(cent + k * LFR_D + d0 + 4);
        cc[k][0]=a.x; cc[k][1]=a.y; cc[k][2]=a.z; cc[k][3]=a.w;
        cc[k][4]=b.x; cc[k][5]=b.y; cc[k][6]=b.z; cc[k][7]=b.w;
    }
    const int r0 = wv * 32;
    #pragma unroll 2
    for (int rr = 0; rr < 32; ++rr) {
        const int r = r0 + rr;
        float m0 = mb[r * 8 + 0], m1 = mb[r * 8 + 1], m2 = mb[r * 8 + 2],
              m3 = mb[r * 8 + 3], m4 = mb[r * 8 + 4];
        float rv[8];
        #pragma unroll
        for (int j = 0; j < 8; ++j) {
            float acc = m0 * cc[0][j];
            acc = fmaf(m1, cc[1][j], acc);
            acc = fmaf(m2, cc[2][j], acc);
            acc = fmaf(m3, cc[3][j], acc);
            acc = fmaf(m4, cc[4][j], acc);
            rv[j] = acc;
        }
        float* orow = out_rec + (size_t)(rb0 + r) * LFR_D + d0;
        ((float4*)orow)[0] = make_float4(rv[0], rv[1], rv[2], rv[3]);
        ((float4*)orow)[1] = make_float4(rv[4], rv[5], rv[6], rv[7]);
    }
}

extern "C" void kernel_launch(void* const* d_in, const int* in_sizes, int n_in,
                              void* d_out, int out_size, void* d_ws, size_t ws_size,
                              hipStream_t stream) {
    const float* x     = (const float*)d_in[0];   // (N, D)
    // d_in[1] = is_protected — unused by the reference computation
    const float* alpha = (const float*)d_in[2];   // (D,)
    const float* w     = (const float*)d_in[3];   // (K, 1)
    const float* cent  = (const float*)d_in[4];   // (K, D)

    float* out   = (float*)d_out;
    float* o_map = out;                                                  // N*K
    float* o_rec = out + (size_t)LFR_N * LFR_K;                          // N*D
    float* o_prd = out + (size_t)LFR_N * LFR_K + (size_t)LFR_N * LFR_D;  // N

    dim3 grid(NBLK), block(TPB);   // 512 blocks x 256 threads, 128 rows/block
    lfr_kernel<<<grid, block, 0, stream>>>(x, alpha, w, cent, o_map, o_rec, o_prd);
}

// Round 5
// 276.904 us; speedup vs baseline: 1.1199x; 1.1199x over previous
//
#include <hip/hip_runtime.h>
#include <math.h>

// Problem constants: N=65536 rows, D=512 features, K=5 centroids.
#define LFR_N 65536
#define LFR_D 512
#define LFR_K 5

// Workspace layout (floats)
#define WS_AC 0        // alpha*c       : K*D = 2560 floats
#define WS_BK 2560     // B_k = sum alpha*c^2 : 5 floats
#define WS_SW 2568     // sigmoid(w)    : 5 floats

// ---------------- prep: tiny one-block kernel filling d_ws ----------------
__global__ __launch_bounds__(512) void lfr_prep(
    const float* __restrict__ alpha, const float* __restrict__ w,
    const float* __restrict__ cent, float* __restrict__ ws)
{
    const int t = threadIdx.x;
    // ac[k*D+d] = alpha[d] * cent[k*D+d]
    for (int f = t; f < LFR_K * LFR_D; f += 512)
        ws[WS_AC + f] = alpha[f & (LFR_D - 1)] * cent[f];
    // B_k: wave wv handles k=wv (waves 0..4), lane covers 8 d's, butterfly-reduce
    const int wv = t >> 6, l = t & 63;
    if (wv < LFR_K) {
        float s = 0.0f;
        #pragma unroll
        for (int j = 0; j < 8; ++j) {
            int d = l * 8 + j;
            float a = alpha[d], c = cent[wv * LFR_D + d];
            s = fmaf(a * c, c, s);
        }
        #pragma unroll
        for (int off = 32; off > 0; off >>= 1) s += __shfl_xor(s, off);
        if (l == 0) ws[WS_BK + wv] = s;
    }
    if (t < LFR_K) ws[WS_SW + t] = 1.0f / (1.0f + __expf(-w[t]));
}

// ---------------- main: one ROW PER THREAD, no LDS, no barriers, no shuffles.
// Lane i scans its own row sequentially (float4); wave covers 64 rows, L1
// absorbs the 8-iteration line reuse. Centroid operands are wave-uniform ->
// s_load streams. dist_k = B_k - 2*dot(x, alpha*c)  (softmax shift-invariant;
// sum alpha*x^2 cancels). R3 post-mortem: barrier-serialized chunk loop sat
// idle at 1.4 TB/s; this removes every sync from the hot path.
__global__ __launch_bounds__(128) void lfr_main(
    const float* __restrict__ x,        // (N, D)
    const float* __restrict__ cent,     // (K, D)
    const float* __restrict__ ws,       // prep outputs
    float* __restrict__ out_map,        // (N, K)
    float* __restrict__ out_rec,        // (N, D)
    float* __restrict__ out_pred)       // (N,)
{
    const int row = blockIdx.x * 128 + threadIdx.x;
    const size_t base = (size_t)row * (LFR_D / 4);

    const float4* __restrict__ x4  = (const float4*)x;
    const float4* __restrict__ ac4 = (const float4*)(ws + WS_AC);
    const float4* __restrict__ c4  = (const float4*)cent;

    // ---- pass 1: dot_k = sum_d x_d * (alpha*c)_kd ----
    float dot[LFR_K] = {0.f, 0.f, 0.f, 0.f, 0.f};
    #pragma unroll 4
    for (int q = 0; q < LFR_D / 4; ++q) {
        float4 xv = x4[base + q];
        #pragma unroll
        for (int k = 0; k < LFR_K; ++k) {
            float4 cq = ac4[k * (LFR_D / 4) + q];   // wave-uniform -> s_load
            dot[k] = fmaf(xv.x, cq.x, dot[k]);
            dot[k] = fmaf(xv.y, cq.y, dot[k]);
            dot[k] = fmaf(xv.z, cq.z, dot[k]);
            dot[k] = fmaf(xv.w, cq.w, dot[k]);
        }
    }

    // ---- softmax over K (per-thread, no reduction anywhere) ----
    float m[LFR_K];
    float mx = -3.402823466e38f;
    #pragma unroll
    for (int k = 0; k < LFR_K; ++k) {
        m[k] = ws[WS_BK + k] - 2.0f * dot[k];       // dist up to row-constant shift
        mx = fmaxf(mx, m[k]);
    }
    float s = 0.0f;
    #pragma unroll
    for (int k = 0; k < LFR_K; ++k) { m[k] = __expf(m[k] - mx); s += m[k]; }
    float inv = 1.0f / s;
    #pragma unroll
    for (int k = 0; k < LFR_K; ++k) m[k] *= inv;

    // ---- mapping + pred ----
    {
        float* mp = out_map + (size_t)row * LFR_K;
        mp[0] = m[0]; mp[1] = m[1]; mp[2] = m[2]; mp[3] = m[3]; mp[4] = m[4];
        float p = 0.0f;
        #pragma unroll
        for (int k = 0; k < LFR_K; ++k) p = fmaf(m[k], ws[WS_SW + k], p);
        out_pred[row] = p;
    }

    // ---- pass 2: rec_d = sum_k m_k * c_kd  (x not needed; cent via s_load) ----
    float4* __restrict__ r4 = (float4*)out_rec;
    #pragma unroll 4
    for (int q = 0; q < LFR_D / 4; ++q) {
        float4 o;
        float4 c0 = c4[0 * (LFR_D / 4) + q];
        float4 c1 = c4[1 * (LFR_D / 4) + q];
        float4 c2 = c4[2 * (LFR_D / 4) + q];
        float4 c3 = c4[3 * (LFR_D / 4) + q];
        float4 cq4 = c4[4 * (LFR_D / 4) + q];
        o.x = fmaf(m[4], cq4.x, fmaf(m[3], c3.x, fmaf(m[2], c2.x, fmaf(m[1], c1.x, m[0] * c0.x))));
        o.y = fmaf(m[4], cq4.y, fmaf(m[3], c3.y, fmaf(m[2], c2.y, fmaf(m[1], c1.y, m[0] * c0.y))));
        o.z = fmaf(m[4], cq4.z, fmaf(m[3], c3.z, fmaf(m[2], c2.z, fmaf(m[1], c1.z, m[0] * c0.z))));
        o.w = fmaf(m[4], cq4.w, fmaf(m[3], c3.w, fmaf(m[2], c2.w, fmaf(m[1], c1.w, m[0] * c0.w))));
        r4[base + q] = o;
    }
}

extern "C" void kernel_launch(void* const* d_in, const int* in_sizes, int n_in,
                              void* d_out, int out_size, void* d_ws, size_t ws_size,
                              hipStream_t stream) {
    const float* x     = (const float*)d_in[0];   // (N, D)
    // d_in[1] = is_protected — unused by the reference computation
    const float* alpha = (const float*)d_in[2];   // (D,)
    const float* w     = (const float*)d_in[3];   // (K, 1)
    const float* cent  = (const float*)d_in[4];   // (K, D)

    float* out   = (float*)d_out;
    float* o_map = out;                                                  // N*K
    float* o_rec = out + (size_t)LFR_N * LFR_K;                          // N*D
    float* o_prd = out + (size_t)LFR_N * LFR_K + (size_t)LFR_N * LFR_D;  // N
    float* ws    = (float*)d_ws;                                         // 10.3 KB used

    lfr_prep<<<dim3(1), dim3(512), 0, stream>>>(alpha, w, cent, ws);
    // 512 blocks x 128 threads = 65536 threads = one row per thread;
    // 2 waves/block, ~4 waves/CU of fat sequential streams.
    lfr_main<<<dim3(LFR_N / 128), dim3(128), 0, stream>>>(
        x, cent, ws, o_map, o_rec, o_prd);
}